// Round 1
// baseline (924.229 us; speedup 1.0000x reference)
//
#include <hip/hip_runtime.h>
#include <utility>

// Problem constants
// DIM_IN=128, DIM_OUT=128, DIM_X=256, L=256, BATCH=8192, fp32 everywhere.
#define NB 8192

// ---------- static_for helper (guarantees compile-time register indices) ----------
template <typename F, size_t... I>
__device__ __forceinline__ void sfor_impl(F&& f, std::index_sequence<I...>) {
  (f(std::integral_constant<int, (int)I>{}), ...);
}
template <int N, typename F>
__device__ __forceinline__ void sfor(F&& f) {
  sfor_impl((F&&)f, std::make_index_sequence<N>{});
}

// ---------- prep: cx[l] = C1[l,:]·x ; xF[k] = Fm[k,:]·x ; rLam = 1/Lam ----------
__global__ __launch_bounds__(256) void k_prep(const float* __restrict__ x,
                                              const float* __restrict__ C1,
                                              const float* __restrict__ Fm,
                                              const float* __restrict__ Lam,
                                              float* __restrict__ cx,
                                              float* __restrict__ xF,
                                              float* __restrict__ rLam) {
  const int t = threadIdx.x;  // 0..255
  float s1 = 0.f, s2 = 0.f;
  for (int i = 0; i < 256; ++i) {
    const float xi = x[i];
    s1 += C1[t * 256 + i] * xi;
    s2 += Fm[t * 256 + i] * xi;
  }
  cx[t] = s1;
  xF[t] = s2;
  rLam[t] = 1.0f / Lam[t];
}

// ---------- in-place Gauss-Jordan inverse of a 128x128 matrix, no pivoting ----------
// Input:  srcT = A^T stored row-major with leading dim `ld` (i.e. A[i][j] = srcT[j*ld+i])
// Output: dstT = (A^{-1})^T row-major, ld 128.
// One block, 256 threads: thread (r = tid&127, half = tid>>7) holds A[r][BASE..BASE+63] in regs.
__global__ __launch_bounds__(256) void k_inv(const float* __restrict__ srcT, int ld,
                                             float* __restrict__ dstT) {
  __shared__ float rowbuf[2][128];
  __shared__ float colbuf[2][128];
  const int tid = threadIdx.x;
  const int r = tid & 127;
  const int BASE = (tid >> 7) * 64;
  float a[64];
#pragma unroll
  for (int j = 0; j < 64; ++j) a[j] = srcT[(BASE + j) * ld + r];
  if (BASE == 0) colbuf[0][r] = a[0];  // initial pivot column (k=0)

  for (int k = 0; k < 128; ++k) {
    const int par = k & 1;
    const int nxt = par ^ 1;
    // publish raw pivot row (both halves' r==k thread writes its 64 cols)
    if (r == k) {
#pragma unroll
      for (int g = 0; g < 16; ++g) {
        float4 v = make_float4(a[4 * g], a[4 * g + 1], a[4 * g + 2], a[4 * g + 3]);
        *(float4*)&rowbuf[par][BASE + 4 * g] = v;
      }
    }
    __syncthreads();
    const float piv = 1.0f / rowbuf[par][k];
    const float t = colbuf[par][r] * piv;  // A[r][k]_current * piv (unused for r==k)
    if (r == k) {
#pragma unroll
      for (int j = 0; j < 64; ++j) a[j] *= piv;
    } else {
#pragma unroll
      for (int g = 0; g < 16; ++g) {
        const float4 rb = *(const float4*)&rowbuf[par][BASE + 4 * g];
        a[4 * g + 0] -= t * rb.x;
        a[4 * g + 1] -= t * rb.y;
        a[4 * g + 2] -= t * rb.z;
        a[4 * g + 3] -= t * rb.w;
      }
    }
    // column-k fixup (register index must be compile-time -> predicated static_for)
    const float fixv = (r == k) ? piv : -t;
    const int fk = k - BASE;      // in [0,64) only for owning half
    const int nk = k + 1 - BASE;  // next pivot column, for colbuf publish
    float ncol = 0.0f;
    sfor<64>([&](auto J) {
      constexpr int jj = decltype(J)::value;
      if (jj == fk) a[jj] = fixv;
      if (jj == nk) ncol = a[jj];
    });
    if ((k + 1 < 128) && (nk >= 0) && (nk < 64)) colbuf[nxt][r] = ncol;
    // parity double-buffering makes a second barrier unnecessary
  }
  __syncthreads();
#pragma unroll
  for (int j = 0; j < 64; ++j) dstT[(BASE + j) * 128 + r] = a[j];  // coalesced in r
}

// ---------- W = invA11 * A12 ; z1 = invA11 * c1   (A = E^T, c = C2^T) ----------
__global__ __launch_bounds__(256) void k_WZ(const float* __restrict__ E,
                                            const float* __restrict__ C2,
                                            const float* __restrict__ inv1T,
                                            float* __restrict__ W,
                                            float* __restrict__ z1) {
  const int gid = blockIdx.x * 256 + threadIdx.x;  // 32768 threads
  const int half = gid >> 14;
  const int idx = gid & 16383;
  const int i = idx >> 7;
  const int j = idx & 127;
  float s = 0.f;
  if (half == 0) {
    // A12[m][j] = E[128+j][m]
    for (int m = 0; m < 128; ++m) s += inv1T[m * 128 + i] * E[(128 + j) * 256 + m];
    W[i * 128 + j] = s;
  } else {
    // c1[m][o] = C2[o][m]   (j plays the role of o)
    for (int m = 0; m < 128; ++m) s += inv1T[m * 128 + i] * C2[j * 256 + m];
    z1[i * 128 + j] = s;
  }
}

// ---------- S^T = (A22 - A21 W)^T ; c2p = c2 - A21 z1 ----------
__global__ __launch_bounds__(256) void k_SC(const float* __restrict__ E,
                                            const float* __restrict__ C2,
                                            const float* __restrict__ W,
                                            const float* __restrict__ z1,
                                            float* __restrict__ STt,
                                            float* __restrict__ c2p) {
  const int gid = blockIdx.x * 256 + threadIdx.x;  // 32768 threads
  if (gid < 16384) {
    const int jj = gid >> 7;  // S column
    const int i = gid & 127;  // S row
    // A22[i][j] = E[128+j][128+i] ; A21[i][m] = E[m][128+i]
    float s = E[(128 + jj) * 256 + 128 + i];
    for (int m = 0; m < 128; ++m) s -= E[m * 256 + 128 + i] * W[m * 128 + jj];
    STt[jj * 128 + i] = s;  // store S transposed
  } else {
    const int idx = gid - 16384;
    const int i = idx >> 7;
    const int o = idx & 127;
    float s = C2[o * 256 + 128 + i];  // c2[i][o] = C2[o][128+i]
    for (int m = 0; m < 128; ++m) s -= E[m * 256 + 128 + i] * z1[m * 128 + o];
    c2p[i * 128 + o] = s;
  }
}

// ---------- g2 = invS * c2p ----------
__global__ __launch_bounds__(256) void k_G2(const float* __restrict__ inv2T,
                                            const float* __restrict__ c2p,
                                            float* __restrict__ g2) {
  const int gid = blockIdx.x * 256 + threadIdx.x;  // 16384
  const int i = gid >> 7;
  const int o = gid & 127;
  float s = 0.f;
  for (int m = 0; m < 128; ++m) s += inv2T[m * 128 + i] * c2p[m * 128 + o];
  g2[i * 128 + o] = s;
}

// ---------- g1 = z1 - W * g2 ----------
__global__ __launch_bounds__(256) void k_G1(const float* __restrict__ W,
                                            const float* __restrict__ z1,
                                            const float* __restrict__ g2,
                                            float* __restrict__ g1) {
  const int gid = blockIdx.x * 256 + threadIdx.x;  // 16384
  const int i = gid >> 7;
  const int o = gid & 127;
  float s = z1[i * 128 + o];
  for (int m = 0; m < 128; ++m) s -= W[i * 128 + m] * g2[m * 128 + o];
  g1[i * 128 + o] = s;
}

// ---------- R = [P | Q] (128 x 384) and y0 ----------
// P[o][l] = D21[o][l] + sum_k G[o][k] B1[k][l],  Q[o][i] = D22[o][i] + sum_k G[o][k] B2[k][i]
// y0[o] = sum_k G[o][k] xF[k] ;  G[o][k] = g1[k][o] (k<128) / g2[k-128][o]
__global__ __launch_bounds__(256) void k_R(const float* __restrict__ B1,
                                           const float* __restrict__ B2,
                                           const float* __restrict__ D21,
                                           const float* __restrict__ D22,
                                           const float* __restrict__ g1,
                                           const float* __restrict__ g2,
                                           const float* __restrict__ xF,
                                           float* __restrict__ R,
                                           float* __restrict__ y0) {
  const int gid = blockIdx.x * 256 + threadIdx.x;  // need 49280
  if (gid < 32768) {
    const int o = gid >> 8;
    const int l = gid & 255;
    float s = D21[o * 256 + l];
    for (int m = 0; m < 128; ++m) {
      s += g1[m * 128 + o] * B1[m * 256 + l];
      s += g2[m * 128 + o] * B1[(128 + m) * 256 + l];
    }
    R[o * 384 + l] = s;
  } else if (gid < 49152) {
    const int t = gid - 32768;
    const int o = t >> 7;
    const int i = t & 127;
    float s = D22[o * 128 + i];
    for (int m = 0; m < 128; ++m) {
      s += g1[m * 128 + o] * B2[m * 128 + i];
      s += g2[m * 128 + o] * B2[(128 + m) * 128 + i];
    }
    R[o * 384 + 256 + i] = s;
  } else if (gid < 49280) {
    const int o = gid - 49152;
    float s = 0.f;
    for (int m = 0; m < 128; ++m) {
      s += g1[m * 128 + o] * xF[m];
      s += g2[m * 128 + o] * xF[128 + m];
    }
    y0[o] = s;
  }
}

// ---------- vw[l][b] = cx[l] + D12[l,:]·u[b,:] ----------
__global__ __launch_bounds__(256) void k_du(const float* __restrict__ u,
                                            const float* __restrict__ D12,
                                            const float* __restrict__ cx,
                                            float* __restrict__ vw) {
  const int b = blockIdx.x * 256 + threadIdx.x;
  const int l0 = blockIdx.y * 16;
  float acc[16];
#pragma unroll
  for (int j = 0; j < 16; ++j) acc[j] = cx[l0 + j];
  for (int i = 0; i < 128; i += 4) {
    const float4 uv = *(const float4*)&u[b * 128 + i];
#pragma unroll
    for (int j = 0; j < 16; ++j) {
      acc[j] += D12[(l0 + j) * 128 + i + 0] * uv.x;
      acc[j] += D12[(l0 + j) * 128 + i + 1] * uv.y;
      acc[j] += D12[(l0 + j) * 128 + i + 2] * uv.z;
      acc[j] += D12[(l0 + j) * 128 + i + 3] * uv.w;
    }
  }
#pragma unroll
  for (int j = 0; j < 16; ++j) vw[(l0 + j) * NB + b] = acc[j];
}

// ---------- sequential 64-step scan chunk (per-thread batch column) ----------
// vw[l][b] holds v-init (cx+du+cross-chunk partial dots); overwritten with w.
__global__ __launch_bounds__(256) void k_scan(const float* __restrict__ D11,
                                              const float* __restrict__ rLam,
                                              float* __restrict__ vw, int c) {
  __shared__ float wl[64][256];  // [k][tid]: bank = tid%32 -> conflict-free
  const int t = threadIdx.x;
  const int b = blockIdx.x * 256 + t;
  const int l0 = c * 64;
  for (int li = 0; li < 64; ++li) {
    const int l = l0 + li;
    float v = vw[l * NB + b];
    const float* drow = D11 + l * 256 + l0;  // uniform across lanes -> scalar loads
    float s0 = 0.f, s1 = 0.f, s2 = 0.f, s3 = 0.f;
    int k = 0;
    for (; k + 3 < li; k += 4) {
      s0 += drow[k + 0] * wl[k + 0][t];
      s1 += drow[k + 1] * wl[k + 1][t];
      s2 += drow[k + 2] * wl[k + 2][t];
      s3 += drow[k + 3] * wl[k + 3][t];
    }
    for (; k < li; ++k) s0 += drow[k] * wl[k][t];
    v += (s0 + s1) + (s2 + s3);
    const float w = tanhf(v * rLam[l]);
    wl[li][t] = w;          // private column, no cross-thread use -> no barrier
    vw[l * NB + b] = w;
  }
}

// ---------- cross-chunk rank-64 update: vw[l'][b] += D11[l', chunk]·w[chunk][b] ----------
__global__ __launch_bounds__(256) void k_upd(const float* __restrict__ D11,
                                             float* __restrict__ vw, int c) {
  const int b = blockIdx.x * 256 + threadIdx.x;
  const int lp0 = (c + 1) * 64 + blockIdx.y * 8;
  const int k0 = c * 64;
  float acc[8];
#pragma unroll
  for (int j = 0; j < 8; ++j) acc[j] = vw[(lp0 + j) * NB + b];
  for (int k = 0; k < 64; ++k) {
    const float wv = vw[(k0 + k) * NB + b];
#pragma unroll
    for (int j = 0; j < 8; ++j) acc[j] += D11[(lp0 + j) * 256 + k0 + k] * wv;
  }
#pragma unroll
  for (int j = 0; j < 8; ++j) vw[(lp0 + j) * NB + b] = acc[j];
}

// ---------- y[b][o] = y0[o] + sum_l R[o][l] w[l][b] + sum_i R[o][256+i] u[b][i] ----------
__global__ __launch_bounds__(256) void k_y(const float* __restrict__ u,
                                           const float* __restrict__ vw,
                                           const float* __restrict__ R,
                                           const float* __restrict__ y0,
                                           float* __restrict__ y) {
  const int b = blockIdx.x * 256 + threadIdx.x;
  const int o0 = blockIdx.y * 16;
  float acc[16];
#pragma unroll
  for (int j = 0; j < 16; ++j) acc[j] = y0[o0 + j];
  for (int l = 0; l < 256; ++l) {
    const float wv = vw[l * NB + b];
#pragma unroll
    for (int j = 0; j < 16; ++j) acc[j] += R[(o0 + j) * 384 + l] * wv;
  }
  for (int i = 0; i < 128; i += 4) {
    const float4 uv = *(const float4*)&u[b * 128 + i];
#pragma unroll
    for (int j = 0; j < 16; ++j) {
      acc[j] += R[(o0 + j) * 384 + 256 + i + 0] * uv.x;
      acc[j] += R[(o0 + j) * 384 + 256 + i + 1] * uv.y;
      acc[j] += R[(o0 + j) * 384 + 256 + i + 2] * uv.z;
      acc[j] += R[(o0 + j) * 384 + 256 + i + 3] * uv.w;
    }
  }
#pragma unroll
  for (int j = 0; j < 16; j += 4) {
    *(float4*)&y[b * 128 + o0 + j] = make_float4(acc[j], acc[j + 1], acc[j + 2], acc[j + 3]);
  }
}

extern "C" void kernel_launch(void* const* d_in, const int* in_sizes, int n_in,
                              void* d_out, int out_size, void* d_ws, size_t ws_size,
                              hipStream_t stream) {
  const float* u   = (const float*)d_in[0];   // (8192,1,128)
  const float* x   = (const float*)d_in[1];   // (1,1,256)
  const float* Fm  = (const float*)d_in[2];   // (256,256)
  const float* B1  = (const float*)d_in[3];   // (256,256)
  const float* B2  = (const float*)d_in[4];   // (256,128)
  const float* C1  = (const float*)d_in[5];   // (256,256)
  const float* C2  = (const float*)d_in[6];   // (128,256)
  const float* D11 = (const float*)d_in[7];   // (256,256) strictly lower
  const float* D12 = (const float*)d_in[8];   // (256,128)
  const float* D21 = (const float*)d_in[9];   // (128,256)
  const float* D22 = (const float*)d_in[10];  // (128,128)
  const float* E   = (const float*)d_in[11];  // (256,256)
  const float* Lam = (const float*)d_in[12];  // (256,)
  float* y = (float*)d_out;                   // (8192,1,128) fp32

  float* F = (float*)d_ws;                    // ~8.7 MB used
  float* vw    = F;                            // 256*8192
  float* SMb   = F + 256 * NB;
  float* inv1T = SMb;                          // 16384
  float* Wm    = SMb + 16384;
  float* z1    = SMb + 32768;
  float* STt   = SMb + 49152;
  float* c2p   = SMb + 65536;
  float* inv2T = SMb + 81920;
  float* g2    = SMb + 98304;
  float* g1    = SMb + 114688;
  float* Rm    = SMb + 131072;                 // 128*384
  float* y0v   = SMb + 180224;                 // 128
  float* cx    = SMb + 180352;                 // 256
  float* xF    = SMb + 180608;                 // 256
  float* rLam  = SMb + 180864;                 // 256

  // small precompute + Schur solve chain for G = C2 * inv(E)  (E^T G^T = C2^T)
  k_prep<<<1, 256, 0, stream>>>(x, C1, Fm, Lam, cx, xF, rLam);
  k_inv<<<1, 256, 0, stream>>>(E, 256, inv1T);          // inv(A11), A = E^T
  k_WZ<<<128, 256, 0, stream>>>(E, C2, inv1T, Wm, z1);
  k_SC<<<128, 256, 0, stream>>>(E, C2, Wm, z1, STt, c2p);
  k_inv<<<1, 256, 0, stream>>>(STt, 128, inv2T);        // inv(S)
  k_G2<<<64, 256, 0, stream>>>(inv2T, c2p, g2);
  k_G1<<<64, 256, 0, stream>>>(Wm, z1, g2, g1);
  k_R<<<193, 256, 0, stream>>>(B1, B2, D21, D22, g1, g2, xF, Rm, y0v);

  // batch pipeline: v-init, chunked scan, output GEMM
  k_du<<<dim3(32, 16), 256, 0, stream>>>(u, D12, cx, vw);
  for (int c = 0; c < 4; ++c) {
    k_scan<<<32, 256, 0, stream>>>(D11, rLam, vw, c);
    if (c < 3) {
      const int tiles = (256 - (c + 1) * 64) / 8;
      k_upd<<<dim3(32, tiles), 256, 0, stream>>>(D11, vw, c);
    }
  }
  k_y<<<dim3(32, 8), 256, 0, stream>>>(u, vw, Rm, y0v, y);
}

// Round 2
// 541.555 us; speedup vs baseline: 1.7066x; 1.7066x over previous
//
#include <hip/hip_runtime.h>
#include <utility>

// Problem constants
// DIM_IN=128, DIM_OUT=128, DIM_X=256, L=256, BATCH=8192, fp32 everywhere.
#define NB 8192

// ---------- static_for helper (guarantees compile-time register indices) ----------
template <typename F, size_t... I>
__device__ __forceinline__ void sfor_impl(F&& f, std::index_sequence<I...>) {
  (f(std::integral_constant<int, (int)I>{}), ...);
}
template <int N, typename F>
__device__ __forceinline__ void sfor(F&& f) {
  sfor_impl((F&&)f, std::make_index_sequence<N>{});
}

// ---------- prep: cx[l] = C1[l,:]·x ; xF[k] = Fm[k,:]·x ; rLam = 1/Lam ----------
__global__ __launch_bounds__(256) void k_prep(const float* __restrict__ x,
                                              const float* __restrict__ C1,
                                              const float* __restrict__ Fm,
                                              const float* __restrict__ Lam,
                                              float* __restrict__ cx,
                                              float* __restrict__ xF,
                                              float* __restrict__ rLam) {
  const int t = threadIdx.x;  // 0..255
  float s1 = 0.f, s2 = 0.f;
  for (int i = 0; i < 256; ++i) {
    const float xi = x[i];
    s1 += C1[t * 256 + i] * xi;
    s2 += Fm[t * 256 + i] * xi;
  }
  cx[t] = s1;
  xF[t] = s2;
  rLam[t] = 1.0f / Lam[t];
}

// ---------- in-place Gauss-Jordan inverse of a 128x128 matrix, no pivoting ----------
// Input:  srcT = A^T stored row-major with leading dim `ld` (i.e. A[i][j] = srcT[j*ld+i])
// Output: dstT = (A^{-1})^T row-major, ld 128.
// 1024 threads: thread (r = tid&127, g = tid>>7) holds A[r][16g..16g+15] in regs.
// The dynamic-register-index fixup (sfor<16>) only runs for the group owning the
// pivot column (wave-coherent branch: group = 128 consecutive tids = 2 waves).
__global__ __launch_bounds__(1024) void k_inv(const float* __restrict__ srcT, int ld,
                                              float* __restrict__ dstT) {
  __shared__ float rowbuf[2][128];
  __shared__ float colbuf[2][128];
  const int tid = threadIdx.x;
  const int r = tid & 127;
  const int BASE = (tid >> 7) * 16;
  float a[16];
#pragma unroll
  for (int j = 0; j < 16; ++j) a[j] = srcT[(BASE + j) * ld + r];
  if (BASE == 0) colbuf[0][r] = a[0];  // initial pivot column (k=0)

  for (int k = 0; k < 128; ++k) {
    const int par = k & 1;
    const int nxt = par ^ 1;
    // publish raw pivot row (each group's r==k thread writes its 16 cols)
    if (r == k) {
#pragma unroll
      for (int g = 0; g < 4; ++g) {
        float4 v = make_float4(a[4 * g], a[4 * g + 1], a[4 * g + 2], a[4 * g + 3]);
        *(float4*)&rowbuf[par][BASE + 4 * g] = v;
      }
    }
    __syncthreads();
    const float piv = 1.0f / rowbuf[par][k];
    const float t = colbuf[par][r] * piv;  // A[r][k]_current * piv (unused for r==k)
    if (r == k) {
#pragma unroll
      for (int j = 0; j < 16; ++j) a[j] *= piv;
    } else {
#pragma unroll
      for (int g = 0; g < 4; ++g) {
        const float4 rb = *(const float4*)&rowbuf[par][BASE + 4 * g];
        a[4 * g + 0] -= t * rb.x;
        a[4 * g + 1] -= t * rb.y;
        a[4 * g + 2] -= t * rb.z;
        a[4 * g + 3] -= t * rb.w;
      }
    }
    // column-k fixup + next-pivot-column publish: only the owning group pays
    const int fk = k - BASE;      // in [0,16) only for owning group
    const int nk = k + 1 - BASE;  // next pivot column
    if (fk >= 0 && fk < 16) {
      const float fixv = (r == k) ? piv : -t;
      sfor<16>([&](auto J) {
        constexpr int jj = decltype(J)::value;
        if (jj == fk) a[jj] = fixv;
      });
    }
    if ((k + 1 < 128) && (nk >= 0) && (nk < 16)) {
      float ncol = 0.0f;
      sfor<16>([&](auto J) {
        constexpr int jj = decltype(J)::value;
        if (jj == nk) ncol = a[jj];
      });
      colbuf[nxt][r] = ncol;
    }
    // parity double-buffering makes a second barrier unnecessary
  }
  __syncthreads();
#pragma unroll
  for (int j = 0; j < 16; ++j) dstT[(BASE + j) * 128 + r] = a[j];  // coalesced in r
}

// ---------- W = invA11 * A12 ; z1 = invA11 * c1   (A = E^T, c = C2^T) ----------
__global__ __launch_bounds__(256) void k_WZ(const float* __restrict__ E,
                                            const float* __restrict__ C2,
                                            const float* __restrict__ inv1T,
                                            float* __restrict__ W,
                                            float* __restrict__ z1) {
  const int gid = blockIdx.x * 256 + threadIdx.x;  // 32768 threads
  const int half = gid >> 14;
  const int idx = gid & 16383;
  const int i = idx >> 7;
  const int j = idx & 127;
  float s = 0.f;
  if (half == 0) {
    // A12[m][j] = E[128+j][m]
    for (int m = 0; m < 128; ++m) s += inv1T[m * 128 + i] * E[(128 + j) * 256 + m];
    W[i * 128 + j] = s;
  } else {
    // c1[m][o] = C2[o][m]   (j plays the role of o)
    for (int m = 0; m < 128; ++m) s += inv1T[m * 128 + i] * C2[j * 256 + m];
    z1[i * 128 + j] = s;
  }
}

// ---------- S^T = (A22 - A21 W)^T ; c2p = c2 - A21 z1 ----------
__global__ __launch_bounds__(256) void k_SC(const float* __restrict__ E,
                                            const float* __restrict__ C2,
                                            const float* __restrict__ W,
                                            const float* __restrict__ z1,
                                            float* __restrict__ STt,
                                            float* __restrict__ c2p) {
  const int gid = blockIdx.x * 256 + threadIdx.x;  // 32768 threads
  if (gid < 16384) {
    const int jj = gid >> 7;  // S column
    const int i = gid & 127;  // S row
    // A22[i][j] = E[128+j][128+i] ; A21[i][m] = E[m][128+i]
    float s = E[(128 + jj) * 256 + 128 + i];
    for (int m = 0; m < 128; ++m) s -= E[m * 256 + 128 + i] * W[m * 128 + jj];
    STt[jj * 128 + i] = s;  // store S transposed
  } else {
    const int idx = gid - 16384;
    const int i = idx >> 7;
    const int o = idx & 127;
    float s = C2[o * 256 + 128 + i];  // c2[i][o] = C2[o][128+i]
    for (int m = 0; m < 128; ++m) s -= E[m * 256 + 128 + i] * z1[m * 128 + o];
    c2p[i * 128 + o] = s;
  }
}

// ---------- g2 = invS * c2p ----------
__global__ __launch_bounds__(256) void k_G2(const float* __restrict__ inv2T,
                                            const float* __restrict__ c2p,
                                            float* __restrict__ g2) {
  const int gid = blockIdx.x * 256 + threadIdx.x;  // 16384
  const int i = gid >> 7;
  const int o = gid & 127;
  float s = 0.f;
  for (int m = 0; m < 128; ++m) s += inv2T[m * 128 + i] * c2p[m * 128 + o];
  g2[i * 128 + o] = s;
}

// ---------- g1 = z1 - W * g2 ----------
__global__ __launch_bounds__(256) void k_G1(const float* __restrict__ W,
                                            const float* __restrict__ z1,
                                            const float* __restrict__ g2,
                                            float* __restrict__ g1) {
  const int gid = blockIdx.x * 256 + threadIdx.x;  // 16384
  const int i = gid >> 7;
  const int o = gid & 127;
  float s = z1[i * 128 + o];
  for (int m = 0; m < 128; ++m) s -= W[i * 128 + m] * g2[m * 128 + o];
  g1[i * 128 + o] = s;
}

// ---------- R = [P | Q] (128 x 384) and y0 ----------
// P[o][l] = D21[o][l] + sum_k G[o][k] B1[k][l],  Q[o][i] = D22[o][i] + sum_k G[o][k] B2[k][i]
// y0[o] = sum_k G[o][k] xF[k] ;  G[o][k] = g1[k][o] (k<128) / g2[k-128][o]
__global__ __launch_bounds__(256) void k_R(const float* __restrict__ B1,
                                           const float* __restrict__ B2,
                                           const float* __restrict__ D21,
                                           const float* __restrict__ D22,
                                           const float* __restrict__ g1,
                                           const float* __restrict__ g2,
                                           const float* __restrict__ xF,
                                           float* __restrict__ R,
                                           float* __restrict__ y0) {
  const int gid = blockIdx.x * 256 + threadIdx.x;  // need 49280
  if (gid < 32768) {
    const int o = gid >> 8;
    const int l = gid & 255;
    float s = D21[o * 256 + l];
    for (int m = 0; m < 128; ++m) {
      s += g1[m * 128 + o] * B1[m * 256 + l];
      s += g2[m * 128 + o] * B1[(128 + m) * 256 + l];
    }
    R[o * 384 + l] = s;
  } else if (gid < 49152) {
    const int t = gid - 32768;
    const int o = t >> 7;
    const int i = t & 127;
    float s = D22[o * 128 + i];
    for (int m = 0; m < 128; ++m) {
      s += g1[m * 128 + o] * B2[m * 128 + i];
      s += g2[m * 128 + o] * B2[(128 + m) * 128 + i];
    }
    R[o * 384 + 256 + i] = s;
  } else if (gid < 49280) {
    const int o = gid - 49152;
    float s = 0.f;
    for (int m = 0; m < 128; ++m) {
      s += g1[m * 128 + o] * xF[m];
      s += g2[m * 128 + o] * xF[128 + m];
    }
    y0[o] = s;
  }
}

// ---------- vw[l][b] = cx[l] + D12[l,:]·u[b,:] ----------
__global__ __launch_bounds__(256) void k_du(const float* __restrict__ u,
                                            const float* __restrict__ D12,
                                            const float* __restrict__ cx,
                                            float* __restrict__ vw) {
  const int b = blockIdx.x * 256 + threadIdx.x;
  const int l0 = blockIdx.y * 16;
  float acc[16];
#pragma unroll
  for (int j = 0; j < 16; ++j) acc[j] = cx[l0 + j];
  for (int i = 0; i < 128; i += 4) {
    const float4 uv = *(const float4*)&u[b * 128 + i];
#pragma unroll
    for (int j = 0; j < 16; ++j) {
      acc[j] += D12[(l0 + j) * 128 + i + 0] * uv.x;
      acc[j] += D12[(l0 + j) * 128 + i + 1] * uv.y;
      acc[j] += D12[(l0 + j) * 128 + i + 2] * uv.z;
      acc[j] += D12[(l0 + j) * 128 + i + 3] * uv.w;
    }
  }
#pragma unroll
  for (int j = 0; j < 16; ++j) vw[(l0 + j) * NB + b] = acc[j];
}

// ---------- sequential 64-step scan chunk, history in REGISTERS, fully unrolled ----
// vw[l][b] holds v-init (cx+du+cross-chunk partial dots); overwritten with w.
// All D11/rLam accesses are wave-uniform -> scalar loads; w[] indices compile-time.
__global__ __launch_bounds__(128) void k_scan(const float* __restrict__ D11,
                                              const float* __restrict__ rLam,
                                              float* __restrict__ vw, int c) {
  const int b = blockIdx.x * 128 + threadIdx.x;
  const int l0 = c * 64;
  float w[64];
  sfor<64>([&](auto LI) {
    constexpr int li = decltype(LI)::value;
    const int l = l0 + li;
    float v = vw[l * NB + b];
    const float* drow = D11 + l * 256 + l0;  // wave-uniform -> s_load
    float s0 = 0.f, s1 = 0.f, s2 = 0.f, s3 = 0.f;
    sfor<li>([&](auto K) {
      constexpr int kk = decltype(K)::value;
      constexpr int lane = kk & 3;
      const float p = drow[kk] * w[kk];
      if (lane == 0) s0 += p;
      if (lane == 1) s1 += p;
      if (lane == 2) s2 += p;
      if (lane == 3) s3 += p;
    });
    v += (s0 + s1) + (s2 + s3);
    const float wv = tanhf(v * rLam[l]);
    w[li] = wv;
    vw[l * NB + b] = wv;
  });
}

// ---------- cross-chunk rank-64 update: vw[l'][b] += D11[l', chunk]·w[chunk][b] ----------
__global__ __launch_bounds__(256) void k_upd(const float* __restrict__ D11,
                                             float* __restrict__ vw, int c) {
  const int b = blockIdx.x * 256 + threadIdx.x;
  const int lp0 = (c + 1) * 64 + blockIdx.y * 8;
  const int k0 = c * 64;
  float acc[8];
#pragma unroll
  for (int j = 0; j < 8; ++j) acc[j] = vw[(lp0 + j) * NB + b];
  for (int k = 0; k < 64; ++k) {
    const float wv = vw[(k0 + k) * NB + b];
#pragma unroll
    for (int j = 0; j < 8; ++j) acc[j] += D11[(lp0 + j) * 256 + k0 + k] * wv;
  }
#pragma unroll
  for (int j = 0; j < 8; ++j) vw[(lp0 + j) * NB + b] = acc[j];
}

// ---------- y[b][o] = y0[o] + sum_l R[o][l] w[l][b] + sum_i R[o][256+i] u[b][i] ----------
__global__ __launch_bounds__(256) void k_y(const float* __restrict__ u,
                                           const float* __restrict__ vw,
                                           const float* __restrict__ R,
                                           const float* __restrict__ y0,
                                           float* __restrict__ y) {
  const int b = blockIdx.x * 256 + threadIdx.x;
  const int o0 = blockIdx.y * 16;
  float acc[16];
#pragma unroll
  for (int j = 0; j < 16; ++j) acc[j] = y0[o0 + j];
  for (int l = 0; l < 256; ++l) {
    const float wv = vw[l * NB + b];
#pragma unroll
    for (int j = 0; j < 16; ++j) acc[j] += R[(o0 + j) * 384 + l] * wv;
  }
  for (int i = 0; i < 128; i += 4) {
    const float4 uv = *(const float4*)&u[b * 128 + i];
#pragma unroll
    for (int j = 0; j < 16; ++j) {
      acc[j] += R[(o0 + j) * 384 + 256 + i + 0] * uv.x;
      acc[j] += R[(o0 + j) * 384 + 256 + i + 1] * uv.y;
      acc[j] += R[(o0 + j) * 384 + 256 + i + 2] * uv.z;
      acc[j] += R[(o0 + j) * 384 + 256 + i + 3] * uv.w;
    }
  }
#pragma unroll
  for (int j = 0; j < 16; j += 4) {
    *(float4*)&y[b * 128 + o0 + j] = make_float4(acc[j], acc[j + 1], acc[j + 2], acc[j + 3]);
  }
}

extern "C" void kernel_launch(void* const* d_in, const int* in_sizes, int n_in,
                              void* d_out, int out_size, void* d_ws, size_t ws_size,
                              hipStream_t stream) {
  const float* u   = (const float*)d_in[0];   // (8192,1,128)
  const float* x   = (const float*)d_in[1];   // (1,1,256)
  const float* Fm  = (const float*)d_in[2];   // (256,256)
  const float* B1  = (const float*)d_in[3];   // (256,256)
  const float* B2  = (const float*)d_in[4];   // (256,128)
  const float* C1  = (const float*)d_in[5];   // (256,256)
  const float* C2  = (const float*)d_in[6];   // (128,256)
  const float* D11 = (const float*)d_in[7];   // (256,256) strictly lower
  const float* D12 = (const float*)d_in[8];   // (256,128)
  const float* D21 = (const float*)d_in[9];   // (128,256)
  const float* D22 = (const float*)d_in[10];  // (128,128)
  const float* E   = (const float*)d_in[11];  // (256,256)
  const float* Lam = (const float*)d_in[12];  // (256,)
  float* y = (float*)d_out;                   // (8192,1,128) fp32

  float* F = (float*)d_ws;                    // ~8.7 MB used
  float* vw    = F;                            // 256*8192
  float* SMb   = F + 256 * NB;
  float* inv1T = SMb;                          // 16384
  float* Wm    = SMb + 16384;
  float* z1    = SMb + 32768;
  float* STt   = SMb + 49152;
  float* c2p   = SMb + 65536;
  float* inv2T = SMb + 81920;
  float* g2    = SMb + 98304;
  float* g1    = SMb + 114688;
  float* Rm    = SMb + 131072;                 // 128*384
  float* y0v   = SMb + 180224;                 // 128
  float* cx    = SMb + 180352;                 // 256
  float* xF    = SMb + 180608;                 // 256
  float* rLam  = SMb + 180864;                 // 256

  // small precompute + Schur solve chain for G = C2 * inv(E)  (E^T G^T = C2^T)
  k_prep<<<1, 256, 0, stream>>>(x, C1, Fm, Lam, cx, xF, rLam);
  k_inv<<<1, 1024, 0, stream>>>(E, 256, inv1T);          // inv(A11), A = E^T
  k_WZ<<<128, 256, 0, stream>>>(E, C2, inv1T, Wm, z1);
  k_SC<<<128, 256, 0, stream>>>(E, C2, Wm, z1, STt, c2p);
  k_inv<<<1, 1024, 0, stream>>>(STt, 128, inv2T);        // inv(S)
  k_G2<<<64, 256, 0, stream>>>(inv2T, c2p, g2);
  k_G1<<<64, 256, 0, stream>>>(Wm, z1, g2, g1);
  k_R<<<193, 256, 0, stream>>>(B1, B2, D21, D22, g1, g2, xF, Rm, y0v);

  // batch pipeline: v-init, chunked scan, output GEMM
  k_du<<<dim3(32, 16), 256, 0, stream>>>(u, D12, cx, vw);
  for (int c = 0; c < 4; ++c) {
    k_scan<<<64, 128, 0, stream>>>(D11, rLam, vw, c);
    if (c < 3) {
      const int tiles = (256 - (c + 1) * 64) / 8;
      k_upd<<<dim3(32, tiles), 256, 0, stream>>>(D11, vw, c);
    }
  }
  k_y<<<dim3(32, 8), 256, 0, stream>>>(u, vw, Rm, y0v, y);
}